// Round 8
// baseline (185.031 us; speedup 1.0000x reference)
//
#include <hip/hip_runtime.h>
#include <math.h>

// Match numpy reference numerics exactly: no FMA contraction anywhere.
// Matching decisions (argmax ties, ov<0.5 threshold) rest on bit-exact floats.
#pragma clang fp contract(off)

#define BB      256
#define PP      3249         // 19*19*9
#define NCLS    21
#define NOBJ    12
#define CELLS   361          // 19*19
#define THRESH_ 0.5f
#define NPB     13           // ceil(PP/256)
#define NROWBLK 3249         // (BB*PP)/256 exactly (831744/256)

// d_out layout (float32): [0]=loss_l/N, [1]=loss_c/N,
// [2 .. 2+BB*CELLS) = conf_t_featuremap, [2+BB*CELLS .. 2+2*BB*CELLS) = have_centerloss

// ---------------------------------------------------------------------------
// K0: IoU matching at full occupancy. Grid (NPB, BB) x 256.
//  - per-prior mi byte: bit7 = (bov >= 0.5), bits 0..3 = best-truth idx (first-max)
//  - per-truth best prior via wave reduce + device atomicMax on
//    key (ov_bits<<32)|(~p)  — exact max-with-smaller-p-tiebreak (iou >= 0).
// ---------------------------------------------------------------------------
__global__ __launch_bounds__(256) void k0_match(
    const float* __restrict__ priors, const float* __restrict__ targets,
    unsigned char* __restrict__ g_mi, unsigned long long* __restrict__ g_best)
{
    const int b = blockIdx.y;
    const int tid = threadIdx.x, lane = tid & 63;
    const int p = blockIdx.x * 256 + tid;
    const bool valid = (p < PP);

    __shared__ float s_tx1[NOBJ], s_ty1[NOBJ], s_tx2[NOBJ], s_ty2[NOBJ], s_area_t[NOBJ];
    if (tid < NOBJ) {
        const float* t = targets + ((size_t)b * NOBJ + tid) * 5;
        float x1 = t[0], y1 = t[1], x2 = t[2], y2 = t[3];
        s_tx1[tid] = x1; s_ty1[tid] = y1; s_tx2[tid] = x2; s_ty2[tid] = y2;
        s_area_t[tid] = (x2 - x1) * (y2 - y1);
    }
    __syncthreads();

    float iou_j[NOBJ];
    float bov = -1.0f; int bidx = 0;
    if (valid) {
        float cx = priors[4*p+0], cy = priors[4*p+1], w = priors[4*p+2], h = priors[4*p+3];
        float px1 = cx - w / 2.0f, py1 = cy - h / 2.0f;
        float px2 = cx + w / 2.0f, py2 = cy + h / 2.0f;
        float area_p = (px2 - px1) * (py2 - py1);
#pragma unroll
        for (int j = 0; j < NOBJ; ++j) {
            float ltx = fmaxf(s_tx1[j], px1);
            float lty = fmaxf(s_ty1[j], py1);
            float rbx = fminf(s_tx2[j], px2);
            float rby = fminf(s_ty2[j], py2);
            float iw = fmaxf(rbx - ltx, 0.0f);
            float ih = fmaxf(rby - lty, 0.0f);
            float inter = iw * ih;
            float iou = inter / ((s_area_t[j] + area_p) - inter);
            iou_j[j] = iou;
            if (iou > bov) { bov = iou; bidx = j; }   // first max over truths
        }
        g_mi[(size_t)b * PP + p] =
            (unsigned char)(((bov < THRESH_) ? 0 : 0x80) | bidx);
    } else {
#pragma unroll
        for (int j = 0; j < NOBJ; ++j) iou_j[j] = -1.0f;
    }

#pragma unroll
    for (int j = 0; j < NOBJ; ++j) {
        float ov = iou_j[j]; int ix = valid ? p : 0x7FFFFFFF;
#pragma unroll
        for (int off = 32; off > 0; off >>= 1) {
            float ov2 = __shfl_xor(ov, off);
            int   ix2 = __shfl_xor(ix, off);
            if (ov2 > ov || (ov2 == ov && ix2 < ix)) { ov = ov2; ix = ix2; }
        }
        if (lane == 0 && ov >= 0.0f) {
            unsigned long long key =
                ((unsigned long long)__float_as_uint(ov) << 32)
                | (unsigned int)(0xFFFFFFFFu - (unsigned int)ix);
            atomicMax(&g_best[b * NOBJ + j], key);
        }
    }
}

// ---------------------------------------------------------------------------
// K1: CE + final conf_t + keys + positives' loss_l, at full occupancy.
// Grid NROWBLK x 256 over flat (b,p) rows; 256 rows staged per block with
// coalesced float4 (block base 21504*blockIdx is 16B aligned; no remainder).
// Forced matches resolved from g_best (L1-hot broadcast reads).
// Op order of lse/ce identical to reference -> bit-exact.
// ---------------------------------------------------------------------------
__global__ __launch_bounds__(256) void k1_ce(
    const float* __restrict__ conf, const float* __restrict__ loc,
    const float* __restrict__ priors, const float* __restrict__ targets,
    const unsigned char* __restrict__ g_mi, const unsigned long long* __restrict__ g_best,
    unsigned long long* __restrict__ g_key, unsigned char* __restrict__ g_ct,
    int* __restrict__ numpos, double* __restrict__ lossl, double* __restrict__ lossc)
{
    __shared__ float s_conf[256 * NCLS];   // 21504 B == 1344 float4
    const int tid = threadIdx.x;
    const size_t row0 = (size_t)blockIdx.x * 256;

    const float4* src = (const float4*)(conf + row0 * NCLS);
    float4* dst = (float4*)s_conf;
#pragma unroll
    for (int i = tid; i < 1344; i += 256) dst[i] = src[i];
    __syncthreads();

    const size_t r = row0 + tid;
    const int b = (int)(r / PP);
    const int p = (int)(r - (size_t)b * PP);

    // Forced-match check: is p some truth's best prior? (last j wins on dups)
    int jov = -1;
#pragma unroll
    for (int j = 0; j < NOBJ; ++j) {
        unsigned long long k = g_best[b * NOBJ + j];
        int bp = (int)(0xFFFFFFFFu - (unsigned int)(k & 0xFFFFFFFFull));
        if (bp == p) jov = j;
    }
    const unsigned char mi = g_mi[r];
    int idx, c;
    if (jov >= 0) {
        idx = jov;
        c = (int)targets[((size_t)b * NOBJ + idx) * 5 + 4] + 1;
    } else {
        idx = mi & 15;
        c = (mi & 0x80) ? ((int)targets[((size_t)b * NOBJ + idx) * 5 + 4] + 1) : 0;
    }
    g_ct[r] = (unsigned char)c;

    // logsumexp + CE from LDS, op order identical to reference.
    const float* cd = s_conf + tid * NCLS;
    float m = cd[0];
#pragma unroll
    for (int k = 1; k < NCLS; ++k) m = fmaxf(m, cd[k]);
    float s = 0.0f;
#pragma unroll
    for (int k = 0; k < NCLS; ++k) s += expf(cd[k] - m);
    float ce = (logf(s) + m) - cd[c];

    float v = (c > 0) ? 0.0f : ce;          // mining value (positives compete as 0)
    g_key[r] = ((unsigned long long)__float_as_uint(v) << 32)
             | (unsigned int)(0xFFFFFFFFu - (unsigned int)p);

    if (c > 0) {
        atomicAdd(&numpos[b], 1);
        atomicAdd(&lossc[b], (double)ce);   // positives are always selected
        const float* t = targets + ((size_t)b * NOBJ + idx) * 5;
        float m0 = t[0], m1 = t[1], m2 = t[2], m3 = t[3];
        float cx = priors[4*p+0], cy = priors[4*p+1], w = priors[4*p+2], h = priors[4*p+3];
        float g0 = ((m0 + m2) / 2.0f - cx) / (0.1f * w);
        float g1 = ((m1 + m3) / 2.0f - cy) / (0.1f * h);
        float g2 = logf((m2 - m0) / w) / 0.2f;
        float g3 = logf((m3 - m1) / h) / 0.2f;
        const float* ld = loc + r * 4;
        float d0 = ld[0] - g0, d1 = ld[1] - g1, d2 = ld[2] - g2, d3 = ld[3] - g3;
        float a0 = fabsf(d0), a1 = fabsf(d1), a2 = fabsf(d2), a3 = fabsf(d3);
        double sl = (double)((a0 < 1.0f) ? 0.5f * d0 * d0 : a0 - 0.5f)
                  + (double)((a1 < 1.0f) ? 0.5f * d1 * d1 : a1 - 0.5f)
                  + (double)((a2 < 1.0f) ? 0.5f * d2 * d2 : a2 - 0.5f)
                  + (double)((a3 < 1.0f) ? 0.5f * d3 * d3 : a3 - 0.5f);
        atomicAdd(&lossl[b], sl);
    }
}

// ---------------------------------------------------------------------------
// K2: per-batch exact radix select + outputs. LDS ~34 KB.
// Keys distinct; order == reference's stable argsort. Key bits 16..31 are
// 0xFFFF for all p < 3249 -> radix rounds d=24,16 skipped (exact).
// ---------------------------------------------------------------------------
__global__ __launch_bounds__(1024) void k2_select(
    const unsigned long long* __restrict__ g_key, const unsigned char* __restrict__ g_ct,
    const int* __restrict__ numpos, double* __restrict__ lossc,
    float* __restrict__ out)
{
    const int b = blockIdx.x, tid = threadIdx.x;
    const int lane = tid & 63, wid = tid >> 6;
    __shared__ unsigned long long s_key[PP];   // 26 KB
    __shared__ unsigned char s_ct[PP];
    __shared__ unsigned char s_sel[PP];
    __shared__ int s_hist[256];
    __shared__ int s_chosen, s_knext;
    __shared__ double s_pc[16];

    const int nneg = min(3 * numpos[b], PP - 1);   // numpos >= 1 (forced matches)

    for (int i = tid; i < PP; i += 1024) {
        s_key[i] = g_key[(size_t)b * PP + i];
        s_ct[i] = g_ct[(size_t)b * PP + i];
    }
    __syncthreads();

    const int ds[6] = {56, 48, 40, 32, 8, 0};
    unsigned long long prefix = 0ull, pmask = 0ull;
    int kk = nneg;
#pragma unroll
    for (int ri = 0; ri < 6; ++ri) {
        const int d = ds[ri];
        if (tid < 256) s_hist[tid] = 0;
        __syncthreads();
        for (int i = tid; i < PP; i += 1024) {
            unsigned long long key = s_key[i];
            if ((key & pmask) == prefix)
                atomicAdd(&s_hist[(int)((key >> d) & 0xFF)], 1);
        }
        __syncthreads();
        if (tid < 64) {   // wave 0: bin where top-down cumulative crosses kk
            int h0 = s_hist[4*lane+0], h1 = s_hist[4*lane+1];
            int h2 = s_hist[4*lane+2], h3 = s_hist[4*lane+3];
            int ls = h0 + h1 + h2 + h3;
            int x = ls;                       // inclusive suffix sum over lanes
#pragma unroll
            for (int off = 1; off < 64; off <<= 1) {
                int y = __shfl_down(x, off);
                if (lane + off < 64) x += y;
            }
            int excl = x - ls;                // sum over lanes > lane
            int cb3 = excl;
            int cb2 = cb3 + h3;
            int cb1 = cb2 + h2;
            int cb0 = cb1 + h1;
            if (cb3 < kk && kk <= cb3 + h3) { s_chosen = 4*lane+3; s_knext = kk - cb3; }
            if (cb2 < kk && kk <= cb2 + h2) { s_chosen = 4*lane+2; s_knext = kk - cb2; }
            if (cb1 < kk && kk <= cb1 + h1) { s_chosen = 4*lane+1; s_knext = kk - cb1; }
            if (cb0 < kk && kk <= cb0 + h0) { s_chosen = 4*lane+0; s_knext = kk - cb0; }
        }
        __syncthreads();
        prefix |= ((unsigned long long)(unsigned int)s_chosen) << d;
        pmask  |= 0xFFull << d;
        kk = s_knext;
        if (d == 32) { prefix |= 0xFFFF0000ull; pmask |= 0xFFFF0000ull; }
        __syncthreads();   // protect s_chosen/s_knext before next round's writes
    }
    const unsigned long long kth = prefix;   // exact nneg-th largest key

    // Selection + negatives' CE (from key upper bits; deterministic reduce).
    double my_c = 0.0;
    for (int p = tid; p < PP; p += 1024) {
        int c = s_ct[p];
        unsigned long long key = s_key[p];
        bool sel = (c > 0) || (key >= kth);
        s_sel[p] = sel ? 1 : 0;
        if (sel && c == 0)
            my_c += (double)__uint_as_float((unsigned int)(key >> 32));
    }
    __syncthreads();

    // Per-cell outputs.
    for (int cI = tid; cI < CELLS; cI += 1024) {
        int mc = 0, hv = 0;
#pragma unroll
        for (int a = 0; a < 9; ++a) {
            int p = cI * 9 + a;
            int cv = s_ct[p];
            mc = (cv > mc) ? cv : mc;
            hv |= s_sel[p];
        }
        out[2 + (size_t)b * CELLS + cI] = (float)mc;
        out[2 + (size_t)BB * CELLS + (size_t)b * CELLS + cI] = (float)hv;
    }

#pragma unroll
    for (int off = 32; off > 0; off >>= 1) my_c += __shfl_down(my_c, off);
    if (lane == 0) s_pc[wid] = my_c;
    __syncthreads();
    if (tid == 0) {
        double L = lossc[b];   // positives' CE accumulated by K1
#pragma unroll
        for (int w2 = 0; w2 < 16; ++w2) L += s_pc[w2];
        lossc[b] = L;
    }
}

__global__ __launch_bounds__(256) void finalize_kernel(
    const int* __restrict__ numpos, const double* __restrict__ lossl,
    const double* __restrict__ lossc, float* __restrict__ out)
{
    __shared__ double s_l[256], s_c[256];
    __shared__ int s_n[256];
    int tid = threadIdx.x;
    s_n[tid] = numpos[tid];     // BB == 256 == blockDim
    s_l[tid] = lossl[tid];
    s_c[tid] = lossc[tid];
    __syncthreads();
    for (int s = 128; s > 0; s >>= 1) {
        if (tid < s) { s_n[tid] += s_n[tid + s]; s_l[tid] += s_l[tid + s]; s_c[tid] += s_c[tid + s]; }
        __syncthreads();
    }
    if (tid == 0) {
        double N = (double)s_n[0];
        out[0] = (float)(s_l[0] / N);
        out[1] = (float)(s_c[0] / N);
    }
}

extern "C" void kernel_launch(void* const* d_in, const int* in_sizes, int n_in,
                              void* d_out, int out_size, void* d_ws, size_t ws_size,
                              hipStream_t stream) {
    const float* loc     = (const float*)d_in[0];  // (B, P, 4)
    const float* conf    = (const float*)d_in[1];  // (B, P, 21)
    const float* priors  = (const float*)d_in[2];  // (P, 4)
    const float* targets = (const float*)d_in[3];  // (B, 12, 5)
    float* out = (float*)d_out;

    // Workspace layout — zero-init block FIRST (one contiguous memset):
    //   lossl[BB] (8B) | lossc[BB] (8B) | best[BB*NOBJ] (8B) | numpos[BB] (4B)
    double* ws_lossl = (double*)d_ws;                                   // BB
    double* ws_lossc = ws_lossl + BB;                                   // BB
    unsigned long long* ws_best = (unsigned long long*)(ws_lossc + BB); // BB*NOBJ
    int*    ws_numpos = (int*)(ws_best + (size_t)BB * NOBJ);            // BB
    const size_t zbytes = (size_t)BB * 8 * 2 + (size_t)BB * NOBJ * 8 + (size_t)BB * 4;
    // Non-zeroed intermediates:
    unsigned long long* ws_key = (unsigned long long*)((char*)d_ws + ((zbytes + 255) & ~(size_t)255));
    unsigned char* ws_ct = (unsigned char*)(ws_key + (size_t)BB * PP);
    unsigned char* ws_mi = ws_ct + (size_t)BB * PP;

    hipMemsetAsync(d_ws, 0, zbytes, stream);

    hipLaunchKernelGGL(k0_match, dim3(NPB, BB), dim3(256), 0, stream,
                       priors, targets, ws_mi, ws_best);
    hipLaunchKernelGGL(k1_ce, dim3(NROWBLK), dim3(256), 0, stream,
                       conf, loc, priors, targets, ws_mi, ws_best,
                       ws_key, ws_ct, ws_numpos, ws_lossl, ws_lossc);
    hipLaunchKernelGGL(k2_select, dim3(BB), dim3(1024), 0, stream,
                       ws_key, ws_ct, ws_numpos, ws_lossc, out);
    hipLaunchKernelGGL(finalize_kernel, dim3(1), dim3(256), 0, stream,
                       ws_numpos, ws_lossl, ws_lossc, out);
}

// Round 9
// 139.410 us; speedup vs baseline: 1.3272x; 1.3272x over previous
//
#include <hip/hip_runtime.h>
#include <math.h>

// Match numpy reference numerics exactly: no FMA contraction anywhere.
// Matching decisions (argmax ties, ov<0.5 threshold) rest on bit-exact floats.
#pragma clang fp contract(off)

#define BB      256
#define PP      3249         // 19*19*9
#define NCLS    21
#define NOBJ    12
#define CELLS   361          // 19*19
#define THRESH_ 0.5f

// 4-float vector with 4-byte alignment: conf rows (84 B) are only dword-aligned;
// gfx950 supports unaligned global wide loads, so this emits dwordx4.
typedef float vf4 __attribute__((ext_vector_type(4), aligned(4)));

// d_out layout (float32): [0]=loss_l/N, [1]=loss_c/N,
// [2 .. 2+BB*CELLS) = conf_t_featuremap, [2+BB*CELLS .. 2+2*BB*CELLS) = have_centerloss

// ---------------------------------------------------------------------------
// Fused per-batch kernel (R5 structure): IoU matching + conf_t + smooth-L1 +
// inline CE + exact radix-select mining + per-cell outputs. One block/batch,
// 1024 threads, LDS ~54 KB.
//   s_key: (ce_bits<<32)|(~p) — distinct keys, order == reference stable argsort
//   s_bov: pass1 best-overlap; reused in pass2 to hold TRUE CE per prior
// Key bits 16..31 are 0xFFFF for all p<3249 -> radix rounds d=24,16 skipped.
// ---------------------------------------------------------------------------
__global__ __launch_bounds__(1024) void fused_kernel(
    const float* __restrict__ loc, const float* __restrict__ conf,
    const float* __restrict__ priors, const float* __restrict__ targets,
    int* __restrict__ numpos, double* __restrict__ lossl,
    double* __restrict__ lossc, float* __restrict__ out)
{
    const int b = blockIdx.x, tid = threadIdx.x;
    const int lane = tid & 63, wid = tid >> 6;   // 16 waves

    __shared__ float s_tx1[NOBJ], s_ty1[NOBJ], s_tx2[NOBJ], s_ty2[NOBJ];
    __shared__ float s_area_t[NOBJ];
    __shared__ int   s_label[NOBJ];
    __shared__ float s_bov[PP];                 // pass1: best ov; pass2+: true CE
    __shared__ short s_bidx[PP];
    __shared__ int   s_bpi[NOBJ];
    __shared__ float s_wov[NOBJ][16];
    __shared__ int   s_widx[NOBJ][16];
    __shared__ unsigned long long s_key[PP];
    __shared__ unsigned char s_ct[PP];
    __shared__ unsigned char s_sel[PP];
    __shared__ int s_hist[256];
    __shared__ int s_chosen, s_knext, s_nneg;
    __shared__ double s_pl[16];
    __shared__ int    s_pn[16];
    __shared__ double s_pc[16];

    if (tid < NOBJ) {
        const float* t = targets + ((size_t)b * NOBJ + tid) * 5;
        float x1 = t[0], y1 = t[1], x2 = t[2], y2 = t[3];
        s_tx1[tid] = x1; s_ty1[tid] = y1; s_tx2[tid] = x2; s_ty2[tid] = y2;
        s_label[tid] = (int)t[4];
        s_area_t[tid] = (x2 - x1) * (y2 - y1);
    }
    __syncthreads();

    // ---- Phase 1: IoU; per-prior best truth (first-max); per-truth best prior.
    float l_bov[NOBJ];
    int   l_bidx[NOBJ];
#pragma unroll
    for (int j = 0; j < NOBJ; ++j) { l_bov[j] = -1.0f; l_bidx[j] = 0x7FFFFFFF; }

    for (int p = tid; p < PP; p += 1024) {
        float cx = priors[4*p+0], cy = priors[4*p+1], w = priors[4*p+2], h = priors[4*p+3];
        float px1 = cx - w / 2.0f, py1 = cy - h / 2.0f;
        float px2 = cx + w / 2.0f, py2 = cy + h / 2.0f;
        float area_p = (px2 - px1) * (py2 - py1);
        float bov = -1.0f; int bidx = 0;
#pragma unroll
        for (int j = 0; j < NOBJ; ++j) {
            float ltx = fmaxf(s_tx1[j], px1);
            float lty = fmaxf(s_ty1[j], py1);
            float rbx = fminf(s_tx2[j], px2);
            float rby = fminf(s_ty2[j], py2);
            float iw = fmaxf(rbx - ltx, 0.0f);
            float ih = fmaxf(rby - lty, 0.0f);
            float inter = iw * ih;
            float iou = inter / ((s_area_t[j] + area_p) - inter);
            if (iou > bov) { bov = iou; bidx = j; }              // first max over truths
            if (iou > l_bov[j]) { l_bov[j] = iou; l_bidx[j] = p; } // best prior for truth j
        }
        s_bov[p] = bov;
        s_bidx[p] = (short)bidx;
    }

    // Wave butterfly reduce per-truth (max, ties -> smaller idx; associative).
#pragma unroll
    for (int j = 0; j < NOBJ; ++j) {
        float ov = l_bov[j]; int ix = l_bidx[j];
#pragma unroll
        for (int off = 32; off > 0; off >>= 1) {
            float ov2 = __shfl_xor(ov, off);
            int   ix2 = __shfl_xor(ix, off);
            if (ov2 > ov || (ov2 == ov && ix2 < ix)) { ov = ov2; ix = ix2; }
        }
        if (lane == 0) { s_wov[j][wid] = ov; s_widx[j][wid] = ix; }
    }
    __syncthreads();
    if (tid < NOBJ) {
        float ov = s_wov[tid][0]; int ix = s_widx[tid][0];
#pragma unroll
        for (int w2 = 1; w2 < 16; ++w2) {
            float ov2 = s_wov[tid][w2]; int ix2 = s_widx[tid][w2];
            if (ov2 > ov || (ov2 == ov && ix2 < ix)) { ov = ov2; ix = ix2; }
        }
        s_bpi[tid] = ix;
    }
    __syncthreads();

    // ---- Phase 2: conf_t + smooth-L1 + inline CE + mining keys.
    // Conf row loaded with 5 unaligned dwordx4 + 1 dword into registers.
    int my_pos = 0;
    double my_lossl = 0.0;
    const float* confb = conf + (size_t)b * PP * NCLS;
    for (int p = tid; p < PP; p += 1024) {
        int jov = -1;
#pragma unroll
        for (int j = 0; j < NOBJ; ++j) if (s_bpi[j] == p) jov = j;  // last-wins on duplicates
        int idx; float ov;
        if (jov >= 0) { idx = jov; ov = 2.0f; }
        else          { idx = (int)s_bidx[p]; ov = s_bov[p]; }
        int c = (ov < THRESH_) ? 0 : (s_label[idx] + 1);
        s_ct[p] = (unsigned char)c;

        // Load the 21-float row into registers (SROA-friendly: constant indices).
        const float* cd = confb + (size_t)p * NCLS;
        const vf4* cd4 = (const vf4*)cd;
        float rw[NCLS];
#pragma unroll
        for (int v = 0; v < 5; ++v) {
            vf4 q = cd4[v];
            rw[4*v+0] = q[0]; rw[4*v+1] = q[1]; rw[4*v+2] = q[2]; rw[4*v+3] = q[3];
        }
        rw[20] = cd[20];

        // CE, op order identical to reference (max order-insensitive; sum strict).
        float m = rw[0];
#pragma unroll
        for (int k = 1; k < NCLS; ++k) m = fmaxf(m, rw[k]);
        float s = 0.0f;
#pragma unroll
        for (int k = 0; k < NCLS; ++k) s += expf(rw[k] - m);
        float cdc = rw[0];
#pragma unroll
        for (int k = 1; k < NCLS; ++k) if (c == k) cdc = rw[k];   // cndmask chain
        float ce = (logf(s) + m) - cdc;

        float v = (c > 0) ? 0.0f : ce;          // mining value (positives compete as 0)
        s_key[p] = ((unsigned long long)__float_as_uint(v) << 32)
                 | (unsigned int)(0xFFFFFFFFu - (unsigned int)p);
        s_bov[p] = ce;                           // true CE (ov dead after read above)

        if (c > 0) {
            ++my_pos;
            float cx = priors[4*p+0], cy = priors[4*p+1], w = priors[4*p+2], h = priors[4*p+3];
            float m0 = s_tx1[idx], m1 = s_ty1[idx], m2 = s_tx2[idx], m3 = s_ty2[idx];
            float g0 = ((m0 + m2) / 2.0f - cx) / (0.1f * w);
            float g1 = ((m1 + m3) / 2.0f - cy) / (0.1f * h);
            float g2 = logf((m2 - m0) / w) / 0.2f;
            float g3 = logf((m3 - m1) / h) / 0.2f;
            const float* ld = loc + ((size_t)b * PP + p) * 4;
            float d0 = ld[0] - g0, d1 = ld[1] - g1, d2 = ld[2] - g2, d3 = ld[3] - g3;
            float a0 = fabsf(d0), a1 = fabsf(d1), a2 = fabsf(d2), a3 = fabsf(d3);
            my_lossl += (double)((a0 < 1.0f) ? 0.5f * d0 * d0 : a0 - 0.5f);
            my_lossl += (double)((a1 < 1.0f) ? 0.5f * d1 * d1 : a1 - 0.5f);
            my_lossl += (double)((a2 < 1.0f) ? 0.5f * d2 * d2 : a2 - 0.5f);
            my_lossl += (double)((a3 < 1.0f) ? 0.5f * d3 * d3 : a3 - 0.5f);
        }
    }
#pragma unroll
    for (int off = 32; off > 0; off >>= 1) {
        my_lossl += __shfl_down(my_lossl, off);
        my_pos   += __shfl_down(my_pos, off);
    }
    if (lane == 0) { s_pl[wid] = my_lossl; s_pn[wid] = my_pos; }
    __syncthreads();
    if (tid == 0) {
        double L = 0.0; int n = 0;
#pragma unroll
        for (int w2 = 0; w2 < 16; ++w2) { L += s_pl[w2]; n += s_pn[w2]; }
        lossl[b] = L; numpos[b] = n;
        s_nneg = min(3 * n, PP - 1);   // n >= 1 (forced matches)
    }
    __syncthreads();

    // ---- Phase 3: exact radix select, 6 effective rounds (d=24,16 skipped:
    // key bits 16..31 are 0xFFFF for every key since p < 3249).
    const int ds[6] = {56, 48, 40, 32, 8, 0};
    unsigned long long prefix = 0ull, pmask = 0ull;
    int kk = s_nneg;
#pragma unroll
    for (int ri = 0; ri < 6; ++ri) {
        const int d = ds[ri];
        if (tid < 256) s_hist[tid] = 0;
        __syncthreads();
        for (int i = tid; i < PP; i += 1024) {
            unsigned long long key = s_key[i];
            if ((key & pmask) == prefix)
                atomicAdd(&s_hist[(int)((key >> d) & 0xFF)], 1);
        }
        __syncthreads();
        if (tid < 64) {   // wave 0: bin where top-down cumulative crosses kk
            int h0 = s_hist[4*lane+0], h1 = s_hist[4*lane+1];
            int h2 = s_hist[4*lane+2], h3 = s_hist[4*lane+3];
            int ls = h0 + h1 + h2 + h3;
            int x = ls;                       // inclusive suffix sum over lanes
#pragma unroll
            for (int off = 1; off < 64; off <<= 1) {
                int y = __shfl_down(x, off);
                if (lane + off < 64) x += y;
            }
            int excl = x - ls;                // sum over lanes > lane
            int cb3 = excl;
            int cb2 = cb3 + h3;
            int cb1 = cb2 + h2;
            int cb0 = cb1 + h1;
            if (cb3 < kk && kk <= cb3 + h3) { s_chosen = 4*lane+3; s_knext = kk - cb3; }
            if (cb2 < kk && kk <= cb2 + h2) { s_chosen = 4*lane+2; s_knext = kk - cb2; }
            if (cb1 < kk && kk <= cb1 + h1) { s_chosen = 4*lane+1; s_knext = kk - cb1; }
            if (cb0 < kk && kk <= cb0 + h0) { s_chosen = 4*lane+0; s_knext = kk - cb0; }
        }
        __syncthreads();
        prefix |= ((unsigned long long)(unsigned int)s_chosen) << d;
        pmask  |= 0xFFull << d;
        kk = s_knext;
        if (d == 32) { prefix |= 0xFFFF0000ull; pmask |= 0xFFFF0000ull; }
        __syncthreads();   // protect s_chosen/s_knext before next round's writes
    }
    const unsigned long long kth = prefix;   // exact nneg-th largest key

    // ---- Phase 4: selection + loss_c (true CE lives in s_bov for all p).
    double my_c = 0.0;
    for (int p = tid; p < PP; p += 1024) {
        int c = s_ct[p];
        bool sel = (c > 0) || (s_key[p] >= kth);
        s_sel[p] = sel ? 1 : 0;
        if (sel) my_c += (double)s_bov[p];
    }
    __syncthreads();

    // ---- Phase 5: per-cell outputs.
    for (int cI = tid; cI < CELLS; cI += 1024) {
        int mc = 0, hv = 0;
#pragma unroll
        for (int a = 0; a < 9; ++a) {
            int p = cI * 9 + a;
            int cv = s_ct[p];
            mc = (cv > mc) ? cv : mc;
            hv |= s_sel[p];
        }
        out[2 + (size_t)b * CELLS + cI] = (float)mc;
        out[2 + (size_t)BB * CELLS + (size_t)b * CELLS + cI] = (float)hv;
    }

#pragma unroll
    for (int off = 32; off > 0; off >>= 1) my_c += __shfl_down(my_c, off);
    if (lane == 0) s_pc[wid] = my_c;
    __syncthreads();
    if (tid == 0) {
        double L = 0.0;
#pragma unroll
        for (int w2 = 0; w2 < 16; ++w2) L += s_pc[w2];
        lossc[b] = L;
    }
}

__global__ __launch_bounds__(256) void finalize_kernel(
    const int* __restrict__ numpos, const double* __restrict__ lossl,
    const double* __restrict__ lossc, float* __restrict__ out)
{
    __shared__ double s_l[256], s_c[256];
    __shared__ int s_n[256];
    int tid = threadIdx.x;
    s_n[tid] = numpos[tid];     // BB == 256 == blockDim
    s_l[tid] = lossl[tid];
    s_c[tid] = lossc[tid];
    __syncthreads();
    for (int s = 128; s > 0; s >>= 1) {
        if (tid < s) { s_n[tid] += s_n[tid + s]; s_l[tid] += s_l[tid + s]; s_c[tid] += s_c[tid + s]; }
        __syncthreads();
    }
    if (tid == 0) {
        double N = (double)s_n[0];
        out[0] = (float)(s_l[0] / N);
        out[1] = (float)(s_c[0] / N);
    }
}

extern "C" void kernel_launch(void* const* d_in, const int* in_sizes, int n_in,
                              void* d_out, int out_size, void* d_ws, size_t ws_size,
                              hipStream_t stream) {
    const float* loc     = (const float*)d_in[0];  // (B, P, 4)
    const float* conf    = (const float*)d_in[1];  // (B, P, 21)
    const float* priors  = (const float*)d_in[2];  // (P, 4)
    const float* targets = (const float*)d_in[3];  // (B, 12, 5)
    float* out = (float*)d_out;

    double* ws_lossl  = (double*)d_ws;             // BB
    double* ws_lossc  = ws_lossl + BB;             // BB
    int*    ws_numpos = (int*)(ws_lossc + BB);     // BB

    hipLaunchKernelGGL(fused_kernel, dim3(BB), dim3(1024), 0, stream,
                       loc, conf, priors, targets, ws_numpos, ws_lossl, ws_lossc, out);
    hipLaunchKernelGGL(finalize_kernel, dim3(1), dim3(256), 0, stream,
                       ws_numpos, ws_lossl, ws_lossc, out);
}